// Round 5
// baseline (344.622 us; speedup 1.0000x reference)
//
#include <hip/hip_runtime.h>
#include <math.h>

#define L_ 8
#define D_ 128
#define B_ 8192
#define P_ 28
#define ALPHA_ 0.1f

typedef __attribute__((ext_vector_type(8))) short bf16x8;
typedef __attribute__((ext_vector_type(4))) float f32x4;
union BF8 { int4 i; bf16x8 h; short s[8]; };

__device__ __forceinline__ short f2bf(float f) {
    unsigned u = __float_as_uint(f);
    unsigned r = (u + 0x7fffu + ((u >> 16) & 1u)) >> 16;   // RNE
    return (short)(r & 0xffffu);
}
__device__ __forceinline__ unsigned rne2(float a, float b) {
    unsigned ua = __float_as_uint(a); ua += 0x7fffu + ((ua >> 16) & 1u);
    unsigned ub = __float_as_uint(b); ub += 0x7fffu + ((ub >> 16) & 1u);
    return __builtin_amdgcn_perm(ub, ua, 0x07060302);      // {b_hi16, a_hi16} -> mem order a,b
}
__device__ __forceinline__ unsigned cvt_pk_bf16(float lo, float hi) {
    unsigned r;
    asm("v_cvt_pk_bf16_f32 %0, %1, %2" : "=v"(r) : "v"(lo), "v"(hi));
    return r;
}
__device__ __forceinline__ float fast_tanh(float x) {
    float e = exp2f(x * 2.885390081777927f);               // e^{2x}
    return 1.f - 2.f * __builtin_amdgcn_rcpf(e + 1.f);
}

// ---------------------------------------------------------------------------
// W transpose -> bf16 fragment layout for DIRECT per-wave global A-frag reads
// (no LDS staging => no XOR swizzle). Per (p,ch) 64KB: byte offset
// kb*8192 + ct*1024 + m*64 + q*16, holding W^T element (k=kb*32+q*8+e,
// hidden=ch*128+ct*16+m). Lane (m,q) of a wave reads 16B; a wave's 64 lanes
// cover one ct-tile's 1KB contiguously (perfect coalescing, zero dup).
// ---------------------------------------------------------------------------
__global__ void transpose_w(const float* __restrict__ W1, const float* __restrict__ W2,
                            short* __restrict__ T1, short* __restrict__ T2) {
    const float* W = blockIdx.y ? W2 : W1;
    short* T = blockIdx.y ? T2 : T1;
    const int p = blockIdx.x >> 3, kb = blockIdx.x & 7;
    __shared__ float tile[32][260];
    const int tid = threadIdx.x;
    for (int s = tid; s < 8192; s += 256) {
        int kk = s >> 8, n = s & 255;
        tile[kk][n] = W[((size_t)p * 256 + kb * 32 + kk) * 256 + n];
    }
    __syncthreads();
    const int n = tid;
    const int ch = n >> 7, ct = (n >> 4) & 7, mm = n & 15;
    const size_t sb = (((size_t)p * 2 + ch) * 64 + kb * 8) * 512;   // kb-slice base (shorts)
    short tmp[32];
#pragma unroll
    for (int kk = 0; kk < 32; ++kk) tmp[kk] = f2bf(tile[kk][n]);
#pragma unroll
    for (int c4 = 0; c4 < 4; ++c4) {
        BF8 u;
#pragma unroll
        for (int e = 0; e < 8; ++e) u.s[e] = tmp[c4 * 8 + e];
        const int byt = ct * 1024 + mm * 64 + c4 * 16;              // linear, no swizzle
        *(int4*)&T[sb + (byt >> 1)] = u.i;
    }
}

// ---------------------------------------------------------------------------
// S (f32) -> bf16 B-fragment layout, computed ONCE. Per 16-row group rg:
// 2048 shorts, elem(row,k) at (k/8 *16 + row%16)*8 + k%8.
// ---------------------------------------------------------------------------
__global__ void prep_s16(const float* __restrict__ S, short* __restrict__ S16) {
    __shared__ __align__(16) short ls[8192];            // 16 KB bounce, bank-swizzled
    const int t = threadIdx.x;
    const size_t base = (size_t)blockIdx.x * 8192;      // 64 rows x 128
#pragma unroll
    for (int rr = 0; rr < 8; ++rr) {
        const int idx = rr * 1024 + t * 4;
        const float4 v = *(const float4*)&S[base + idx];
        const int row = idx >> 7, col = idx & 127;
        const int rgl = row >> 4, mr = row & 15, kq = col >> 3, c4 = (col >> 2) & 1;
        const unsigned w0 = rne2(v.x, v.y), w1 = rne2(v.z, v.w);
        const int byt = (rgl * 4096 + kq * 256 + mr * 16 + c4 * 8) ^ ((kq & 7) << 4);
        *(uint2*)((char*)ls + byt) = (uint2){w0, w1};
    }
    __syncthreads();
#pragma unroll
    for (int r = 0; r < 4; ++r) {
        const int un = r * 256 + t;                      // 16-B unit
        const int kq = (un >> 4) & 15;
        const int byt = (un * 16) ^ ((kq & 7) << 4);
        *(int4*)&S16[base + (size_t)un * 8] = *(const int4*)((const char*)ls + byt);
    }
}

// ---------------------------------------------------------------------------
// Fused per-layer kernel, block = (layer k, 64 rows).
// KEY CHANGE vs round 3: W A-frags are read DIRECTLY from global (L2) into
// registers -- W is L2-resident (7.3 MB) and each wave's frag is a disjoint
// coalesced 1KB slice, so LDS-staging it bought nothing and cost 168
// vmcnt(0)-draining barriers per block (~1500 cyc/phase, the whole 217 us).
// Now: G1/G2 are barrier-free unrolled load+MFMA streams; only Hs (tanh ->
// G2 operand) stays in LDS with 2 barriers per partner-iter (14 total).
// blockIdx.x = k so bid%8 == k: each XCD's blocks share one layer's W
// working set (1.34 MB, fits 4 MB per-XCD L2).
// ---------------------------------------------------------------------------
__launch_bounds__(256, 3)
__global__ void fused(const float* __restrict__ S, const float* __restrict__ ES,
                      const float* __restrict__ b1, const float* __restrict__ b2,
                      const short* __restrict__ S16, const short* __restrict__ T1,
                      const short* __restrict__ T2, float* __restrict__ OUT) {
    __shared__ __align__(16) short Hs[16384];     // 32 KB: full h tile, fragment layout
    const int k = blockIdx.x, rb = blockIdx.y;
    const int tid = threadIdx.x, lane = tid & 63, w = tid >> 6;
    const int m = lane & 15, q = lane >> 4;
    char* const hsb = (char*)Hs;
    const int afo = w * 1024 + m * 32 + q * 8;    // A-frag lane offset (shorts), at*512 extra

    // u init: wave w owns d-slice [w*32, w*32+32), 64 rows
    const size_t srow = (size_t)k * B_ + rb * 64;
    f32x4 u[2][4];
#pragma unroll
    for (int at = 0; at < 2; ++at)
#pragma unroll
        for (int nt = 0; nt < 4; ++nt)
            u[at][nt] = *(const f32x4*)&S[(srow + nt * 16 + m) * D_ + w * 32 + at * 16 + q * 4];

    for (int it = 0; it < 7; ++it) {
        const int mp = it + (it >= k ? 1 : 0);     // partner (ascending = global pair order)
        const int li = k < mp ? k : mp;
        const int lj = k < mp ? mp : k;
        const int p  = li * 7 - ((li * (li - 1)) >> 1) + (lj - li - 1);
        const int side = (k == li) ? 0 : 1;
        const float es = ES[li * L_ + lj];
        const float st = 1.f / (1.f + expf(-es));

        // ============ G1: both hidden halves -> full H in LDS (no barriers) ====
        for (int hh = 0; hh < 2; ++hh) {
            const short* wA = T1 + ((size_t)(p * 2 + hh) << 15) + afo;
            f32x4 acc1[2][4];
#pragma unroll
            for (int at = 0; at < 2; ++at) {
                const f32x4 bv = *(const f32x4*)&b1[p * 256 + hh * 128 + w * 32 + at * 16 + q * 4];
#pragma unroll
                for (int nt = 0; nt < 4; ++nt) acc1[at][nt] = bv;
            }
#pragma unroll
            for (int kb = 0; kb < 8; ++kb) {
                const int lb = (kb < 4) ? li : lj;          // comb = [s_i | s_j]
                const int kbl = kb & 3;
                const bf16x8 A0 = *(const bf16x8*)(wA + kb * 4096);
                const bf16x8 A1 = *(const bf16x8*)(wA + kb * 4096 + 512);
                const short* sp = S16 + ((size_t)lb * 512 + rb * 4) * 2048
                                      + ((kbl * 4 + q) * 16 + m) * 8;
#pragma unroll
                for (int nt = 0; nt < 4; ++nt) {
                    const bf16x8 Bf = *(const bf16x8*)(sp + nt * 2048);
                    acc1[0][nt] = __builtin_amdgcn_mfma_f32_16x16x32_bf16(A0, Bf, acc1[0][nt], 0, 0, 0);
                    acc1[1][nt] = __builtin_amdgcn_mfma_f32_16x16x32_bf16(A1, Bf, acc1[1][nt], 0, 0, 0);
                }
            }
            // tanh -> bf16 -> Hs in FRAGMENT layout (conflict-free 8B stores):
            // hidden = hh*128 + (w*2+at)*16 + q*4 + rr, row = nt*16+m
            // byte = nt*8192 + (hidden/8)*256 + m*16 + (q&1)*8
#pragma unroll
            for (int at = 0; at < 2; ++at) {
                const int cb = (hh * 16 + w * 4 + at * 2 + (q >> 1)) * 256 + m * 16 + (q & 1) * 8;
#pragma unroll
                for (int nt = 0; nt < 4; ++nt) {
                    const float v0 = fast_tanh(acc1[at][nt][0]);
                    const float v1 = fast_tanh(acc1[at][nt][1]);
                    const float v2 = fast_tanh(acc1[at][nt][2]);
                    const float v3 = fast_tanh(acc1[at][nt][3]);
                    const unsigned p0 = cvt_pk_bf16(v0, v1);
                    const unsigned p1 = cvt_pk_bf16(v2, v3);
                    *(uint2*)(hsb + nt * 8192 + cb) = (uint2){p0, p1};
                }
            }
        }
        __syncthreads();                           // full H visible to all waves

        // ============ G2 over full K=256, output = side's 128 cols (no barriers)
        const short* wA2 = T2 + ((size_t)(p * 2 + side) << 15) + afo;
        f32x4 acc2[2][4];
#pragma unroll
        for (int at = 0; at < 2; ++at)
#pragma unroll
            for (int nt = 0; nt < 4; ++nt) acc2[at][nt] = (f32x4){0.f, 0.f, 0.f, 0.f};

#pragma unroll
        for (int kb = 0; kb < 8; ++kb) {
            const bf16x8 A0 = *(const bf16x8*)(wA2 + kb * 4096);
            const bf16x8 A1 = *(const bf16x8*)(wA2 + kb * 4096 + 512);
            const int hc = (kb * 4 + q) * 256 + m * 16;      // fragment-layout read
#pragma unroll
            for (int nt = 0; nt < 4; ++nt) {
                const bf16x8 Hf = *(const bf16x8*)(hsb + nt * 8192 + hc);
                acc2[0][nt] = __builtin_amdgcn_mfma_f32_16x16x32_bf16(A0, Hf, acc2[0][nt], 0, 0, 0);
                acc2[1][nt] = __builtin_amdgcn_mfma_f32_16x16x32_bf16(A1, Hf, acc2[1][nt], 0, 0, 0);
            }
        }

        // ---- sequential propagation step (exact reference order, f32) ----
#pragma unroll
        for (int at = 0; at < 2; ++at) {
            const f32x4 bv = *(const f32x4*)&b2[p * 256 + side * 128 + w * 32 + at * 16 + q * 4];
#pragma unroll
            for (int nt = 0; nt < 4; ++nt)
#pragma unroll
                for (int r = 0; r < 4; ++r) {
                    const float e = st * (acc2[at][nt][r] + bv[r]);
                    u[at][nt][r] += ALPHA_ * (e - u[at][nt][r]);
                }
        }
        __syncthreads();                           // all G2 reads done before next tanh-store
    }

#pragma unroll
    for (int nt = 0; nt < 4; ++nt)
#pragma unroll
        for (int at = 0; at < 2; ++at)
            *(f32x4*)&OUT[(srow + nt * 16 + m) * D_ + w * 32 + at * 16 + q * 4] = u[at][nt];
}

// measures analytically constant (lam1 == 1 after normalize):
// (127+127-255)*1e-12*(-ln 1e-12) = -2.7631021115928547e-11
__global__ void fill_meas(float* __restrict__ M) {
    int t = blockIdx.x * 256 + threadIdx.x;
    if (t < P_ * B_) M[t] = -2.7631021115928547e-11f;
}

extern "C" void kernel_launch(void* const* d_in, const int* in_sizes, int n_in,
                              void* d_out, int out_size, void* d_ws, size_t ws_size,
                              hipStream_t stream) {
    const float* S  = (const float*)d_in[0];
    const float* ES = (const float*)d_in[1];
    const float* W1 = (const float*)d_in[2];
    const float* b1 = (const float*)d_in[3];
    const float* W2 = (const float*)d_in[4];
    const float* b2 = (const float*)d_in[5];

    short* S16 = (short*)d_ws;                           // 8*8192*128 shorts = 16.8 MB
    short* T1  = S16 + (size_t)L_ * B_ * D_;             // 56*32768 shorts = 3.67 MB
    short* T2  = T1 + (size_t)P_ * 2 * 32768;            // 3.67 MB  (total 24.1 MB)

    float* OUT  = (float*)d_out;                         // updated [L,B,D]
    float* MEAS = OUT + (size_t)L_ * B_ * D_;            // measures [P,B]

    transpose_w<<<dim3(P_ * 8, 2), 256, 0, stream>>>(W1, W2, T1, T2);
    prep_s16<<<dim3(1024), 256, 0, stream>>>(S, S16);
    fused<<<dim3(8, 128), 256, 0, stream>>>(S, ES, b1, b2, S16, T1, T2, OUT);
    fill_meas<<<dim3(896), 256, 0, stream>>>(MEAS);
}

// Round 6
// 301.934 us; speedup vs baseline: 1.1414x; 1.1414x over previous
//
#include <hip/hip_runtime.h>
#include <math.h>

#define L_ 8
#define D_ 128
#define B_ 8192
#define P_ 28
#define ALPHA_ 0.1f

typedef __attribute__((ext_vector_type(8))) short bf16x8;
typedef __attribute__((ext_vector_type(4))) float f32x4;
union BF8 { int4 i; bf16x8 h; short s[8]; };

__device__ __forceinline__ short f2bf(float f) {
    unsigned u = __float_as_uint(f);
    unsigned r = (u + 0x7fffu + ((u >> 16) & 1u)) >> 16;   // RNE
    return (short)(r & 0xffffu);
}
__device__ __forceinline__ unsigned rne2(float a, float b) {
    unsigned ua = __float_as_uint(a); ua += 0x7fffu + ((ua >> 16) & 1u);
    unsigned ub = __float_as_uint(b); ub += 0x7fffu + ((ub >> 16) & 1u);
    return __builtin_amdgcn_perm(ub, ua, 0x07060302);      // {b_hi16, a_hi16} -> mem order a,b
}
__device__ __forceinline__ unsigned cvt_pk_bf16(float lo, float hi) {
    unsigned r;
    asm("v_cvt_pk_bf16_f32 %0, %1, %2" : "=v"(r) : "v"(lo), "v"(hi));
    return r;
}
__device__ __forceinline__ float fast_tanh(float x) {
    float e = exp2f(x * 2.885390081777927f);               // e^{2x}
    return 1.f - 2.f * __builtin_amdgcn_rcpf(e + 1.f);
}

// ---------------------------------------------------------------------------
// W transpose -> bf16 fragment layout for DIRECT per-wave global A-frag reads.
// Per (p,ch) 64KB: byte offset kb*8192 + ct*1024 + m*64 + q*16, holding W^T
// element (k=kb*32+q*8+e, hidden=ch*128+ct*16+m). A wave's 64 lanes cover one
// ct-tile's 1KB contiguously (perfect coalescing, zero dup).
// ---------------------------------------------------------------------------
__global__ void transpose_w(const float* __restrict__ W1, const float* __restrict__ W2,
                            short* __restrict__ T1, short* __restrict__ T2) {
    const float* W = blockIdx.y ? W2 : W1;
    short* T = blockIdx.y ? T2 : T1;
    const int p = blockIdx.x >> 3, kb = blockIdx.x & 7;
    __shared__ float tile[32][260];
    const int tid = threadIdx.x;
    for (int s = tid; s < 8192; s += 256) {
        int kk = s >> 8, n = s & 255;
        tile[kk][n] = W[((size_t)p * 256 + kb * 32 + kk) * 256 + n];
    }
    __syncthreads();
    const int n = tid;
    const int ch = n >> 7, ct = (n >> 4) & 7, mm = n & 15;
    const size_t sb = (((size_t)p * 2 + ch) * 64 + kb * 8) * 512;   // kb-slice base (shorts)
    short tmp[32];
#pragma unroll
    for (int kk = 0; kk < 32; ++kk) tmp[kk] = f2bf(tile[kk][n]);
#pragma unroll
    for (int c4 = 0; c4 < 4; ++c4) {
        BF8 u;
#pragma unroll
        for (int e = 0; e < 8; ++e) u.s[e] = tmp[c4 * 8 + e];
        const int byt = ct * 1024 + mm * 64 + c4 * 16;              // linear
        *(int4*)&T[sb + (byt >> 1)] = u.i;
    }
}

// ---------------------------------------------------------------------------
// S (f32) -> bf16 B-fragment layout, computed ONCE. Per 16-row group rg:
// 2048 shorts, elem(row,k) at (k/8 *16 + row%16)*8 + k%8.
// ---------------------------------------------------------------------------
__global__ void prep_s16(const float* __restrict__ S, short* __restrict__ S16) {
    __shared__ __align__(16) short ls[8192];            // 16 KB bounce, bank-swizzled
    const int t = threadIdx.x;
    const size_t base = (size_t)blockIdx.x * 8192;      // 64 rows x 128
#pragma unroll
    for (int rr = 0; rr < 8; ++rr) {
        const int idx = rr * 1024 + t * 4;
        const float4 v = *(const float4*)&S[base + idx];
        const int row = idx >> 7, col = idx & 127;
        const int rgl = row >> 4, mr = row & 15, kq = col >> 3, c4 = (col >> 2) & 1;
        const unsigned w0 = rne2(v.x, v.y), w1 = rne2(v.z, v.w);
        const int byt = (rgl * 4096 + kq * 256 + mr * 16 + c4 * 8) ^ ((kq & 7) << 4);
        *(uint2*)((char*)ls + byt) = (uint2){w0, w1};
    }
    __syncthreads();
#pragma unroll
    for (int r = 0; r < 4; ++r) {
        const int un = r * 256 + t;                      // 16-B unit
        const int kq = (un >> 4) & 15;
        const int byt = (un * 16) ^ ((kq & 7) << 4);
        *(int4*)&S16[base + (size_t)un * 8] = *(const int4*)((const char*)ls + byt);
    }
}

// ---------------------------------------------------------------------------
// Fused per-layer kernel, block = (layer k, 128 rows), 512 threads / 8 waves.
// Wave (wr,wc): wr in {0,1} owns a 64-row half, wc in {0..3} a 32-col slice.
// vs round 5 (64-row/256-thr, 256 us, latency-bound @ 24% occupancy):
//  * W fragment traffic HALVED (same 192 KB/iter serves 128 rows; A-frags
//    shared by wr-pairs through L1)
//  * 2 blocks/CU x 8 waves = 16 waves/CU (4/SIMD) doubles latency hiding
//  * G1's global B-frags get an explicit one-kb-ahead register prefetch
// Per-wave register tiles unchanged (u[2][4], acc[2][4]) -> no spill risk.
// ---------------------------------------------------------------------------
__launch_bounds__(512, 4)
__global__ void fused(const float* __restrict__ S, const float* __restrict__ ES,
                      const float* __restrict__ b1, const float* __restrict__ b2,
                      const short* __restrict__ S16, const short* __restrict__ T1,
                      const short* __restrict__ T2, float* __restrict__ OUT) {
    __shared__ __align__(16) short Hs[32768];     // 64 KB: full h tile (128 x 256), frag layout
    const int k = blockIdx.x, rb = blockIdx.y;
    const int tid = threadIdx.x, lane = tid & 63, w = tid >> 6;
    const int wr = w >> 2, wc = w & 3;
    const int m = lane & 15, q = lane >> 4;
    char* const hsb = (char*)Hs;
    const int afo = wc * 1024 + m * 32 + q * 8;   // A-frag lane offset (shorts); +at*512

    // u init: wave owns rows [wr*64, wr*64+64), cols [wc*32, wc*32+32)
    const size_t srow = (size_t)k * B_ + rb * 128;
    f32x4 u[2][4];
#pragma unroll
    for (int at = 0; at < 2; ++at)
#pragma unroll
        for (int nt = 0; nt < 4; ++nt)
            u[at][nt] = *(const f32x4*)&S[(srow + wr * 64 + nt * 16 + m) * D_
                                          + wc * 32 + at * 16 + q * 4];

    for (int it = 0; it < 7; ++it) {
        const int mp = it + (it >= k ? 1 : 0);     // partner (ascending = global pair order)
        const int li = k < mp ? k : mp;
        const int lj = k < mp ? mp : k;
        const int p  = li * 7 - ((li * (li - 1)) >> 1) + (lj - li - 1);
        const int side = (k == li) ? 0 : 1;
        const float es = ES[li * L_ + lj];
        const float st = 1.f / (1.f + expf(-es));

        // B-frag bases for this block's row-slab (layer li / lj)
        const short* biL = S16 + ((size_t)li * 512 + rb * 8 + wr * 4) * 2048 + (q * 16 + m) * 8;
        const short* biJ = S16 + ((size_t)lj * 512 + rb * 8 + wr * 4) * 2048 + (q * 16 + m) * 8;

        // ============ G1: both hidden halves -> full H in LDS (no barriers) ====
        for (int hh = 0; hh < 2; ++hh) {
            const short* wA = T1 + ((size_t)(p * 2 + hh) << 15) + afo;
            f32x4 acc1[2][4];
#pragma unroll
            for (int at = 0; at < 2; ++at) {
                const f32x4 bv = *(const f32x4*)&b1[p * 256 + hh * 128 + wc * 32 + at * 16 + q * 4];
#pragma unroll
                for (int nt = 0; nt < 4; ++nt) acc1[at][nt] = bv;
            }
            bf16x8 Bc[4], Bn[4];
#pragma unroll
            for (int nt = 0; nt < 4; ++nt) Bc[nt] = *(const bf16x8*)(biL + nt * 2048);
#pragma unroll
            for (int kb = 0; kb < 8; ++kb) {
                if (kb < 7) {                       // prefetch next kb's B-frags
                    const int kn = kb + 1;
                    const short* spn = ((kn < 4) ? biL : biJ) + (kn & 3) * 512;
#pragma unroll
                    for (int nt = 0; nt < 4; ++nt) Bn[nt] = *(const bf16x8*)(spn + nt * 2048);
                }
                const bf16x8 A0 = *(const bf16x8*)(wA + kb * 4096);
                const bf16x8 A1 = *(const bf16x8*)(wA + kb * 4096 + 512);
#pragma unroll
                for (int nt = 0; nt < 4; ++nt) {
                    acc1[0][nt] = __builtin_amdgcn_mfma_f32_16x16x32_bf16(A0, Bc[nt], acc1[0][nt], 0, 0, 0);
                    acc1[1][nt] = __builtin_amdgcn_mfma_f32_16x16x32_bf16(A1, Bc[nt], acc1[1][nt], 0, 0, 0);
                }
#pragma unroll
                for (int nt = 0; nt < 4; ++nt) Bc[nt] = Bn[nt];
            }
            // tanh -> bf16 -> Hs in FRAGMENT layout (conflict-free 8B stores):
            // hidden = hh*128 + (wc*2+at)*16 + q*4 + rr, row = wr*64 + nt*16 + m
            // byte = (wr*4+nt)*8192 + (hidden/8)*256 + m*16 + (q&1)*8
#pragma unroll
            for (int at = 0; at < 2; ++at) {
                const int cb = (hh * 16 + wc * 4 + at * 2 + (q >> 1)) * 256 + m * 16 + (q & 1) * 8;
#pragma unroll
                for (int nt = 0; nt < 4; ++nt) {
                    const float v0 = fast_tanh(acc1[at][nt][0]);
                    const float v1 = fast_tanh(acc1[at][nt][1]);
                    const float v2 = fast_tanh(acc1[at][nt][2]);
                    const float v3 = fast_tanh(acc1[at][nt][3]);
                    const unsigned p0 = cvt_pk_bf16(v0, v1);
                    const unsigned p1 = cvt_pk_bf16(v2, v3);
                    *(uint2*)(hsb + (wr * 4 + nt) * 8192 + cb) = (uint2){p0, p1};
                }
            }
        }
        __syncthreads();                           // full H visible to all waves

        // ============ G2 over full K=256, output = side's 128 cols =============
        const short* wA2 = T2 + ((size_t)(p * 2 + side) << 15) + afo;
        f32x4 acc2[2][4];
#pragma unroll
        for (int at = 0; at < 2; ++at)
#pragma unroll
            for (int nt = 0; nt < 4; ++nt) acc2[at][nt] = (f32x4){0.f, 0.f, 0.f, 0.f};

#pragma unroll
        for (int kb = 0; kb < 8; ++kb) {
            const bf16x8 A0 = *(const bf16x8*)(wA2 + kb * 4096);
            const bf16x8 A1 = *(const bf16x8*)(wA2 + kb * 4096 + 512);
            const int hc = (kb * 4 + q) * 256 + m * 16;      // fragment-layout read
#pragma unroll
            for (int nt = 0; nt < 4; ++nt) {
                const bf16x8 Hf = *(const bf16x8*)(hsb + (wr * 4 + nt) * 8192 + hc);
                acc2[0][nt] = __builtin_amdgcn_mfma_f32_16x16x32_bf16(A0, Hf, acc2[0][nt], 0, 0, 0);
                acc2[1][nt] = __builtin_amdgcn_mfma_f32_16x16x32_bf16(A1, Hf, acc2[1][nt], 0, 0, 0);
            }
        }

        // ---- sequential propagation step (exact reference order, f32) ----
#pragma unroll
        for (int at = 0; at < 2; ++at) {
            const f32x4 bv = *(const f32x4*)&b2[p * 256 + side * 128 + wc * 32 + at * 16 + q * 4];
#pragma unroll
            for (int nt = 0; nt < 4; ++nt)
#pragma unroll
                for (int r = 0; r < 4; ++r) {
                    const float e = st * (acc2[at][nt][r] + bv[r]);
                    u[at][nt][r] += ALPHA_ * (e - u[at][nt][r]);
                }
        }
        __syncthreads();                           // all G2 reads done before next tanh-store
    }

#pragma unroll
    for (int nt = 0; nt < 4; ++nt)
#pragma unroll
        for (int at = 0; at < 2; ++at)
            *(f32x4*)&OUT[(srow + wr * 64 + nt * 16 + m) * D_ + wc * 32 + at * 16 + q * 4] = u[at][nt];
}

// measures analytically constant (lam1 == 1 after normalize):
// (127+127-255)*1e-12*(-ln 1e-12) = -2.7631021115928547e-11
__global__ void fill_meas(float* __restrict__ M) {
    int t = blockIdx.x * 256 + threadIdx.x;
    if (t < P_ * B_) M[t] = -2.7631021115928547e-11f;
}

extern "C" void kernel_launch(void* const* d_in, const int* in_sizes, int n_in,
                              void* d_out, int out_size, void* d_ws, size_t ws_size,
                              hipStream_t stream) {
    const float* S  = (const float*)d_in[0];
    const float* ES = (const float*)d_in[1];
    const float* W1 = (const float*)d_in[2];
    const float* b1 = (const float*)d_in[3];
    const float* W2 = (const float*)d_in[4];
    const float* b2 = (const float*)d_in[5];

    short* S16 = (short*)d_ws;                           // 8*8192*128 shorts = 16.8 MB
    short* T1  = S16 + (size_t)L_ * B_ * D_;             // 56*32768 shorts = 3.67 MB
    short* T2  = T1 + (size_t)P_ * 2 * 32768;            // 3.67 MB  (total 24.1 MB)

    float* OUT  = (float*)d_out;                         // updated [L,B,D]
    float* MEAS = OUT + (size_t)L_ * B_ * D_;            // measures [P,B]

    transpose_w<<<dim3(P_ * 8, 2), 256, 0, stream>>>(W1, W2, T1, T2);
    prep_s16<<<dim3(1024), 256, 0, stream>>>(S, S16);
    fused<<<dim3(8, 64), 512, 0, stream>>>(S, ES, b1, b2, S16, T1, T2, OUT);
    fill_meas<<<dim3(896), 256, 0, stream>>>(MEAS);
}

// Round 8
// 284.962 us; speedup vs baseline: 1.2094x; 1.0596x over previous
//
#include <hip/hip_runtime.h>
#include <math.h>

#define L_ 8
#define D_ 128
#define B_ 8192
#define P_ 28
#define ALPHA_ 0.1f

typedef __attribute__((ext_vector_type(8))) short bf16x8;
typedef __attribute__((ext_vector_type(4))) float f32x4;
union BF8 { int4 i; bf16x8 h; short s[8]; };

__device__ __forceinline__ short f2bf(float f) {
    unsigned u = __float_as_uint(f);
    unsigned r = (u + 0x7fffu + ((u >> 16) & 1u)) >> 16;   // RNE
    return (short)(r & 0xffffu);
}
__device__ __forceinline__ unsigned rne2(float a, float b) {
    unsigned ua = __float_as_uint(a); ua += 0x7fffu + ((ua >> 16) & 1u);
    unsigned ub = __float_as_uint(b); ub += 0x7fffu + ((ub >> 16) & 1u);
    return __builtin_amdgcn_perm(ub, ua, 0x07060302);      // {b_hi16, a_hi16} -> mem order a,b
}
__device__ __forceinline__ unsigned cvt_pk_bf16(float lo, float hi) {
    unsigned r;
    asm("v_cvt_pk_bf16_f32 %0, %1, %2" : "=v"(r) : "v"(lo), "v"(hi));
    return r;
}
__device__ __forceinline__ float fast_tanh(float x) {
    float e = exp2f(x * 2.885390081777927f);               // e^{2x}
    return 1.f - 2.f * __builtin_amdgcn_rcpf(e + 1.f);
}

// ---------------------------------------------------------------------------
// W transpose -> bf16 fragment layout for DIRECT per-wave global A-frag reads.
// Per (p,ch) 64KB: byte offset kb*8192 + ct*1024 + m*64 + q*16, holding W^T
// element (k=kb*32+q*8+e, hidden=ch*128+ct*16+m). A wave's 64 lanes cover one
// ct-tile's 1KB contiguously (perfect coalescing, zero dup).
// ---------------------------------------------------------------------------
__global__ void transpose_w(const float* __restrict__ W1, const float* __restrict__ W2,
                            short* __restrict__ T1, short* __restrict__ T2) {
    const float* W = blockIdx.y ? W2 : W1;
    short* T = blockIdx.y ? T2 : T1;
    const int p = blockIdx.x >> 3, kb = blockIdx.x & 7;
    __shared__ float tile[32][260];
    const int tid = threadIdx.x;
    for (int s = tid; s < 8192; s += 256) {
        int kk = s >> 8, n = s & 255;
        tile[kk][n] = W[((size_t)p * 256 + kb * 32 + kk) * 256 + n];
    }
    __syncthreads();
    const int n = tid;
    const int ch = n >> 7, ct = (n >> 4) & 7, mm = n & 15;
    const size_t sb = (((size_t)p * 2 + ch) * 64 + kb * 8) * 512;   // kb-slice base (shorts)
    short tmp[32];
#pragma unroll
    for (int kk = 0; kk < 32; ++kk) tmp[kk] = f2bf(tile[kk][n]);
#pragma unroll
    for (int c4 = 0; c4 < 4; ++c4) {
        BF8 u;
#pragma unroll
        for (int e = 0; e < 8; ++e) u.s[e] = tmp[c4 * 8 + e];
        const int byt = ct * 1024 + mm * 64 + c4 * 16;              // linear
        *(int4*)&T[sb + (byt >> 1)] = u.i;
    }
}

// ---------------------------------------------------------------------------
// S (f32) -> bf16 B-fragment layout, computed ONCE. Per 16-row group rg:
// 2048 shorts, elem(row,k) at (k/8 *16 + row%16)*8 + k%8.
// ---------------------------------------------------------------------------
__global__ void prep_s16(const float* __restrict__ S, short* __restrict__ S16) {
    __shared__ __align__(16) short ls[8192];            // 16 KB bounce, bank-swizzled
    const int t = threadIdx.x;
    const size_t base = (size_t)blockIdx.x * 8192;      // 64 rows x 128
#pragma unroll
    for (int rr = 0; rr < 8; ++rr) {
        const int idx = rr * 1024 + t * 4;
        const float4 v = *(const float4*)&S[base + idx];
        const int row = idx >> 7, col = idx & 127;
        const int rgl = row >> 4, mr = row & 15, kq = col >> 3, c4 = (col >> 2) & 1;
        const unsigned w0 = rne2(v.x, v.y), w1 = rne2(v.z, v.w);
        const int byt = (rgl * 4096 + kq * 256 + mr * 16 + c4 * 8) ^ ((kq & 7) << 4);
        *(uint2*)((char*)ls + byt) = (uint2){w0, w1};
    }
    __syncthreads();
#pragma unroll
    for (int r = 0; r < 4; ++r) {
        const int un = r * 256 + t;                      // 16-B unit
        const int kq = (un >> 4) & 15;
        const int byt = (un * 16) ^ ((kq & 7) << 4);
        *(int4*)&S16[base + (size_t)un * 8] = *(const int4*)((const char*)ls + byt);
    }
}

// ---------------------------------------------------------------------------
// Fused per-layer kernel, block = (layer k, 128 rows), 512 threads / 8 waves.
// Wave (wr,wc): wr in {0,1} owns a 64-row half, wc in {0..3} a 32-col slice.
// vs round 6: ONLY change is __launch_bounds__(512,4) -> (512,3).
// (512,4) capped the unified file at 128 regs/wave; compiler split 64 arch
// + 64 AGPR and spilled ~36 regs of {u, Bc/Bn, addr} -> 267 MB scratch
// round-trip = the entire 220 us (WRITE_SIZE 299 MB vs 32 MB ideal).
// (512,3) caps at ~170 regs: live set ~132 fits. Occupancy 13.6 -> ~12
// waves/CU -- a 12% TLP haircut traded against removing ~534 MB of traffic.
// ---------------------------------------------------------------------------
__launch_bounds__(512, 3)
__global__ void fused(const float* __restrict__ S, const float* __restrict__ ES,
                      const float* __restrict__ b1, const float* __restrict__ b2,
                      const short* __restrict__ S16, const short* __restrict__ T1,
                      const short* __restrict__ T2, float* __restrict__ OUT) {
    __shared__ __align__(16) short Hs[32768];     // 64 KB: full h tile (128 x 256), frag layout
    const int k = blockIdx.x, rb = blockIdx.y;
    const int tid = threadIdx.x, lane = tid & 63, w = tid >> 6;
    const int wr = w >> 2, wc = w & 3;
    const int m = lane & 15, q = lane >> 4;
    char* const hsb = (char*)Hs;
    const int afo = wc * 1024 + m * 32 + q * 8;   // A-frag lane offset (shorts); +at*512

    // u init: wave owns rows [wr*64, wr*64+64), cols [wc*32, wc*32+32)
    const size_t srow = (size_t)k * B_ + rb * 128;
    f32x4 u[2][4];
#pragma unroll
    for (int at = 0; at < 2; ++at)
#pragma unroll
        for (int nt = 0; nt < 4; ++nt)
            u[at][nt] = *(const f32x4*)&S[(srow + wr * 64 + nt * 16 + m) * D_
                                          + wc * 32 + at * 16 + q * 4];

    for (int it = 0; it < 7; ++it) {
        const int mp = it + (it >= k ? 1 : 0);     // partner (ascending = global pair order)
        const int li = k < mp ? k : mp;
        const int lj = k < mp ? mp : k;
        const int p  = li * 7 - ((li * (li - 1)) >> 1) + (lj - li - 1);
        const int side = (k == li) ? 0 : 1;
        const float es = ES[li * L_ + lj];
        const float st = 1.f / (1.f + expf(-es));

        // B-frag bases for this block's row-slab (layer li / lj)
        const short* biL = S16 + ((size_t)li * 512 + rb * 8 + wr * 4) * 2048 + (q * 16 + m) * 8;
        const short* biJ = S16 + ((size_t)lj * 512 + rb * 8 + wr * 4) * 2048 + (q * 16 + m) * 8;

        // ============ G1: both hidden halves -> full H in LDS (no barriers) ====
        for (int hh = 0; hh < 2; ++hh) {
            const short* wA = T1 + ((size_t)(p * 2 + hh) << 15) + afo;
            f32x4 acc1[2][4];
#pragma unroll
            for (int at = 0; at < 2; ++at) {
                const f32x4 bv = *(const f32x4*)&b1[p * 256 + hh * 128 + wc * 32 + at * 16 + q * 4];
#pragma unroll
                for (int nt = 0; nt < 4; ++nt) acc1[at][nt] = bv;
            }
            bf16x8 Bc[4], Bn[4];
#pragma unroll
            for (int nt = 0; nt < 4; ++nt) Bc[nt] = *(const bf16x8*)(biL + nt * 2048);
#pragma unroll
            for (int kb = 0; kb < 8; ++kb) {
                if (kb < 7) {                       // prefetch next kb's B-frags
                    const int kn = kb + 1;
                    const short* spn = ((kn < 4) ? biL : biJ) + (kn & 3) * 512;
#pragma unroll
                    for (int nt = 0; nt < 4; ++nt) Bn[nt] = *(const bf16x8*)(spn + nt * 2048);
                }
                const bf16x8 A0 = *(const bf16x8*)(wA + kb * 4096);
                const bf16x8 A1 = *(const bf16x8*)(wA + kb * 4096 + 512);
#pragma unroll
                for (int nt = 0; nt < 4; ++nt) {
                    acc1[0][nt] = __builtin_amdgcn_mfma_f32_16x16x32_bf16(A0, Bc[nt], acc1[0][nt], 0, 0, 0);
                    acc1[1][nt] = __builtin_amdgcn_mfma_f32_16x16x32_bf16(A1, Bc[nt], acc1[1][nt], 0, 0, 0);
                }
#pragma unroll
                for (int nt = 0; nt < 4; ++nt) Bc[nt] = Bn[nt];
            }
            // tanh -> bf16 -> Hs in FRAGMENT layout (conflict-free 8B stores):
            // hidden = hh*128 + (wc*2+at)*16 + q*4 + rr, row = wr*64 + nt*16 + m
            // byte = (wr*4+nt)*8192 + (hidden/8)*256 + m*16 + (q&1)*8
#pragma unroll
            for (int at = 0; at < 2; ++at) {
                const int cb = (hh * 16 + wc * 4 + at * 2 + (q >> 1)) * 256 + m * 16 + (q & 1) * 8;
#pragma unroll
                for (int nt = 0; nt < 4; ++nt) {
                    const float v0 = fast_tanh(acc1[at][nt][0]);
                    const float v1 = fast_tanh(acc1[at][nt][1]);
                    const float v2 = fast_tanh(acc1[at][nt][2]);
                    const float v3 = fast_tanh(acc1[at][nt][3]);
                    const unsigned p0 = cvt_pk_bf16(v0, v1);
                    const unsigned p1 = cvt_pk_bf16(v2, v3);
                    *(uint2*)(hsb + (wr * 4 + nt) * 8192 + cb) = (uint2){p0, p1};
                }
            }
        }
        __syncthreads();                           // full H visible to all waves

        // ============ G2 over full K=256, output = side's 128 cols =============
        const short* wA2 = T2 + ((size_t)(p * 2 + side) << 15) + afo;
        f32x4 acc2[2][4];
#pragma unroll
        for (int at = 0; at < 2; ++at)
#pragma unroll
            for (int nt = 0; nt < 4; ++nt) acc2[at][nt] = (f32x4){0.f, 0.f, 0.f, 0.f};

#pragma unroll
        for (int kb = 0; kb < 8; ++kb) {
            const bf16x8 A0 = *(const bf16x8*)(wA2 + kb * 4096);
            const bf16x8 A1 = *(const bf16x8*)(wA2 + kb * 4096 + 512);
            const int hc = (kb * 4 + q) * 256 + m * 16;      // fragment-layout read
#pragma unroll
            for (int nt = 0; nt < 4; ++nt) {
                const bf16x8 Hf = *(const bf16x8*)(hsb + (wr * 4 + nt) * 8192 + hc);
                acc2[0][nt] = __builtin_amdgcn_mfma_f32_16x16x32_bf16(A0, Hf, acc2[0][nt], 0, 0, 0);
                acc2[1][nt] = __builtin_amdgcn_mfma_f32_16x16x32_bf16(A1, Hf, acc2[1][nt], 0, 0, 0);
            }
        }

        // ---- sequential propagation step (exact reference order, f32) ----
#pragma unroll
        for (int at = 0; at < 2; ++at) {
            const f32x4 bv = *(const f32x4*)&b2[p * 256 + side * 128 + wc * 32 + at * 16 + q * 4];
#pragma unroll
            for (int nt = 0; nt < 4; ++nt)
#pragma unroll
                for (int r = 0; r < 4; ++r) {
                    const float e = st * (acc2[at][nt][r] + bv[r]);
                    u[at][nt][r] += ALPHA_ * (e - u[at][nt][r]);
                }
        }
        __syncthreads();                           // all G2 reads done before next tanh-store
    }

#pragma unroll
    for (int nt = 0; nt < 4; ++nt)
#pragma unroll
        for (int at = 0; at < 2; ++at)
            *(f32x4*)&OUT[(srow + wr * 64 + nt * 16 + m) * D_ + wc * 32 + at * 16 + q * 4] = u[at][nt];
}

// measures analytically constant (lam1 == 1 after normalize):
// (127+127-255)*1e-12*(-ln 1e-12) = -2.7631021115928547e-11
__global__ void fill_meas(float* __restrict__ M) {
    int t = blockIdx.x * 256 + threadIdx.x;
    if (t < P_ * B_) M[t] = -2.7631021115928547e-11f;
}

extern "C" void kernel_launch(void* const* d_in, const int* in_sizes, int n_in,
                              void* d_out, int out_size, void* d_ws, size_t ws_size,
                              hipStream_t stream) {
    const float* S  = (const float*)d_in[0];
    const float* ES = (const float*)d_in[1];
    const float* W1 = (const float*)d_in[2];
    const float* b1 = (const float*)d_in[3];
    const float* W2 = (const float*)d_in[4];
    const float* b2 = (const float*)d_in[5];

    short* S16 = (short*)d_ws;                           // 8*8192*128 shorts = 16.8 MB
    short* T1  = S16 + (size_t)L_ * B_ * D_;             // 56*32768 shorts = 3.67 MB
    short* T2  = T1 + (size_t)P_ * 2 * 32768;            // 3.67 MB  (total 24.1 MB)

    float* OUT  = (float*)d_out;                         // updated [L,B,D]
    float* MEAS = OUT + (size_t)L_ * B_ * D_;            // measures [P,B]

    transpose_w<<<dim3(P_ * 8, 2), 256, 0, stream>>>(W1, W2, T1, T2);
    prep_s16<<<dim3(1024), 256, 0, stream>>>(S, S16);
    fused<<<dim3(8, 64), 512, 0, stream>>>(S, ES, b1, b2, S16, T1, T2, OUT);
    fill_meas<<<dim3(896), 256, 0, stream>>>(MEAS);
}